// Round 7
// baseline (2402.862 us; speedup 1.0000x reference)
//
#include <hip/hip_runtime.h>
#include <stdint.h>
#include <math.h>

#define NN 12288
#define DD 128
#define KTOP 31
#define TILE 128
#define GB (NN / TILE)   // 96
#define TCAND 64         // verified: top-64 by bf16 key, bucket-inclusive
#define CCAP 128         // compaction capacity (R6-verified)
#define CAP 1536         // per-row candidate capacity (24/lane)
#define TAUN 512         // tau sample columns
#define TAURANK 24       // tau = 24th largest of sample, minus one bucket

typedef __attribute__((ext_vector_type(8))) short bf16x8;
typedef __attribute__((ext_vector_type(4))) float f32x4;

__device__ __forceinline__ unsigned short f2bf(float x) {  // RNE, no NaN in our data
  unsigned int u = __float_as_uint(x);
  u += 0x7fffu + ((u >> 16) & 1u);
  return (unsigned short)(u >> 16);
}
__device__ __forceinline__ float bf2f(unsigned int us) {
  return __uint_as_float((us & 0xFFFFu) << 16);
}

// ---------------- Kernel 1: MLP (Linear-ReLU-Linear) + L2 normalize, fp64; taps fp64 + bf16 ----------------
__global__ __launch_bounds__(128)
void mlp_norm_kernel(const float* __restrict__ feat,
                     const float* __restrict__ W1, const float* __restrict__ b1,
                     const float* __restrict__ W2, const float* __restrict__ b2,
                     double* __restrict__ hn64, unsigned short* __restrict__ hnb) {
  __shared__ double bufA[8][DD];
  __shared__ double bufB[8][DD];
  __shared__ double mnorm[8];
  const int t = threadIdx.x;
  const int row0 = blockIdx.x * 8;

  #pragma unroll
  for (int rr = 0; rr < 8; ++rr)
    bufA[rr][t] = (double)feat[(size_t)(row0 + rr) * DD + t];
  __syncthreads();

  {
    double acc[8] = {0,0,0,0,0,0,0,0};
    const float* wrow = W1 + (size_t)t * DD;
    for (int k = 0; k < DD; ++k) {
      double w = (double)wrow[k];
      #pragma unroll
      for (int rr = 0; rr < 8; ++rr)
        acc[rr] = fma(w, bufA[rr][k], acc[rr]);
    }
    double bb = (double)b1[t];
    #pragma unroll
    for (int rr = 0; rr < 8; ++rr)
      bufB[rr][t] = fmax(acc[rr] + bb, 0.0);
  }
  __syncthreads();
  {
    double acc[8] = {0,0,0,0,0,0,0,0};
    const float* wrow = W2 + (size_t)t * DD;
    for (int k = 0; k < DD; ++k) {
      double w = (double)wrow[k];
      #pragma unroll
      for (int rr = 0; rr < 8; ++rr)
        acc[rr] = fma(w, bufB[rr][k], acc[rr]);
    }
    double bb = (double)b2[t];
    #pragma unroll
    for (int rr = 0; rr < 8; ++rr)
      bufA[rr][t] = acc[rr] + bb;
  }
  __syncthreads();

  const int lane = t & 63;
  const int w = t >> 6;
  #pragma unroll
  for (int r2 = 0; r2 < 4; ++r2) {
    int rr = w * 4 + r2;
    double x0 = bufA[rr][lane];
    double x1 = bufA[rr][lane + 64];
    double s = x0 * x0 + x1 * x1;
    #pragma unroll
    for (int d = 1; d < 64; d <<= 1)
      s += __shfl_xor(s, d);
    if (lane == 0) mnorm[rr] = fmax(sqrt(s), 1e-12);
  }
  __syncthreads();
  #pragma unroll
  for (int rr = 0; rr < 8; ++rr) {
    double v = bufA[rr][t] / mnorm[rr];
    hn64[(size_t)(row0 + rr) * DD + t] = v;
    hnb[(size_t)(row0 + rr) * DD + t] = f2bf((float)v);
  }
}

// ---------------- Kernel 2: per-row tau from 512-col sample ----------------
// One wave per row. Lane s-th col: c = lane + 64*s, s<8. fp32 dot on
// dequantized bf16 (matches MFMA fp32 accumulation to <<1 key bucket).
// tau[row] = (24th largest bf16-key of the sample) - 1 bucket.
// P(tau > true bf16-rank-64 key) = P(Binom(512, 64/12288) >= 24) ~ 2e-15/row.
__global__ __launch_bounds__(256)
void tau_kernel(const unsigned short* __restrict__ hnb,
                unsigned short* __restrict__ tau) {
  __shared__ unsigned short rowbuf[4 * DD];
  const int t = threadIdx.x, lane = t & 63, wv = t >> 6;
  const int row0 = blockIdx.x * 4;
  ((unsigned*)rowbuf)[t] = ((const unsigned*)(hnb + (size_t)row0 * DD))[t];
  __syncthreads();
  const unsigned short* rb = rowbuf + wv * DD;

  float acc[8] = {0,0,0,0,0,0,0,0};
  for (int k8 = 0; k8 < DD; k8 += 8) {
    float rv[8];
    #pragma unroll
    for (int e = 0; e < 8; ++e) rv[e] = bf2f(rb[k8 + e]);   // wave-uniform broadcast
    #pragma unroll
    for (int s = 0; s < 8; ++s) {
      uint4 cv = *(const uint4*)(hnb + (size_t)(lane + 64 * s) * DD + k8);
      unsigned wd[4] = {cv.x, cv.y, cv.z, cv.w};
      #pragma unroll
      for (int q = 0; q < 4; ++q) {
        acc[s] = fmaf(bf2f(wd[q]), rv[2 * q], acc[s]);
        acc[s] = fmaf(bf2f(wd[q] >> 16), rv[2 * q + 1], acc[s]);
      }
    }
  }
  unsigned key[8];
  #pragma unroll
  for (int s = 0; s < 8; ++s) {
    unsigned bf = f2bf(acc[s]);
    key[s] = (bf & 0x8000u) ? 0u : bf;
  }
  unsigned lo = 0, hi = 0xFFFFu;
  while (lo < hi) {
    unsigned mid = (lo + hi + 1) >> 1;
    int c = 0;
    #pragma unroll
    for (int s = 0; s < 8; ++s) c += (int)(key[s] >= mid);
    #pragma unroll
    for (int d = 1; d < 64; d <<= 1) c += __shfl_xor(c, d);
    if (c >= TAURANK) lo = mid; else hi = mid - 1;
  }
  if (lane == 0) tau[row0 + wv] = (unsigned short)(lo ? lo - 1 : 0);
}

// ---------------- Kernel 3: bf16 MFMA GEMM + threshold filter -> candidate push ----------------
__device__ __forceinline__ int lunit(int c, int r, int q) {
  return c * 512 + r * 4 + ((q + (r >> 1)) & 3);
}

__global__ __launch_bounds__(256)
void gemm_filter_kernel(const unsigned short* __restrict__ hnb,
                        const unsigned short* __restrict__ tau,
                        int* __restrict__ cnt, unsigned* __restrict__ cand) {
  __shared__ __attribute__((aligned(16))) unsigned short At[16384];  // 32 KB
  __shared__ __attribute__((aligned(16))) unsigned short Bt[16384];  // 32 KB
  const int t = threadIdx.x;
  const int lane = t & 63;
  const int wv = t >> 6;
  const int bi = blockIdx.x / GB, bj = blockIdx.x % GB;
  const int r0 = bi * TILE, c0 = bj * TILE;

  #pragma unroll
  for (int i = 0; i < 8; ++i) {
    int u = i * 256 + t;
    int c = u >> 9, r = (u >> 2) & 127, g = u & 3;
    int q = (g - (r >> 1)) & 3;
    uint4 v = *(const uint4*)(hnb + (size_t)(r0 + r) * DD + c * 32 + q * 8);
    *(uint4*)(At + u * 8) = v;
  }
  #pragma unroll
  for (int i = 0; i < 8; ++i) {
    int u = i * 256 + t;
    int c = u >> 9, r = (u >> 2) & 127, g = u & 3;
    int q = (g - (r >> 1)) & 3;
    uint4 v = *(const uint4*)(hnb + (size_t)(c0 + r) * DD + c * 32 + q * 8);
    *(uint4*)(Bt + u * 8) = v;
  }
  __syncthreads();

  const int wr = (wv >> 1) * 64;
  const int wc = (wv & 1) * 64;
  const int m = lane & 15, quad = lane >> 4;

  f32x4 acc[4][4] = {};
  #pragma unroll
  for (int kc = 0; kc < 4; ++kc) {
    bf16x8 a[4], b[4];
    #pragma unroll
    for (int i = 0; i < 4; ++i)
      a[i] = *(const bf16x8*)(At + lunit(kc, wr + i * 16 + m, quad) * 8);
    #pragma unroll
    for (int j = 0; j < 4; ++j)
      b[j] = *(const bf16x8*)(Bt + lunit(kc, wc + j * 16 + m, quad) * 8);
    #pragma unroll
    for (int i = 0; i < 4; ++i)
      #pragma unroll
      for (int j = 0; j < 4; ++j)
        acc[i][j] = __builtin_amdgcn_mfma_f32_16x16x32_bf16(a[i], b[j], acc[i][j], 0, 0, 0);
  }

  // filter epilogue: per lane 16 rows x 4 cols; key >= tau[row] -> atomic push
  unsigned short tr[4][4];
  #pragma unroll
  for (int i = 0; i < 4; ++i)
    #pragma unroll
    for (int r = 0; r < 4; ++r)
      tr[i][r] = tau[r0 + wr + i * 16 + quad * 4 + r];

  #pragma unroll
  for (int i = 0; i < 4; ++i)
    #pragma unroll
    for (int j = 0; j < 4; ++j)
      #pragma unroll
      for (int r = 0; r < 4; ++r) {
        float v = acc[i][j][r];
        unsigned bf = f2bf(v);
        unsigned key = (bf & 0x8000u) ? 0u : bf;
        if (key >= (unsigned)tr[i][r]) {
          int R = r0 + wr + i * 16 + quad * 4 + r;
          int C = c0 + wc + j * 16 + m;
          int idx = atomicAdd(&cnt[R], 1);
          if (idx < CAP) cand[(size_t)R * CAP + idx] = (key << 16) | (unsigned)C;
        }
      }
}

// ---------------- Kernel 4: candidate select (R6-verified semantics) + fp64 rescore ----------------
// One wave per row. Binary search largest thr with count(key >= thr) >= 64
// over the candidate multiset (== full-row count for thr >= tau), compaction
// cap 128, fp64 rescore 2/lane (verified R2 math), 31x tie-exact extract.
__global__ __launch_bounds__(256)
void rescore_kernel(const unsigned* __restrict__ cand, const int* __restrict__ cnt,
                    const double* __restrict__ hn64,
                    float* __restrict__ resval, int* __restrict__ rescol) {
  __shared__ unsigned scand[4][CCAP];
  const int t = threadIdx.x, lane = t & 63, wv = t >> 6;
  const int row = blockIdx.x * 4 + wv;
  int n = cnt[row];
  n = n > CAP ? CAP : n;

  unsigned ck[CAP / 64];
  #pragma unroll
  for (int i = 0; i < CAP / 64; ++i) {
    int idx = lane + 64 * i;
    ck[i] = (idx < n) ? cand[(size_t)row * CAP + idx] : 0u;
  }

  unsigned lo = 0, hi = 0xFFFFu;
  while (lo < hi) {
    unsigned mid = (lo + hi + 1) >> 1;
    int c = 0;
    #pragma unroll
    for (int i = 0; i < CAP / 64; ++i) c += (int)((ck[i] >> 16) >= mid);
    #pragma unroll
    for (int d = 1; d < 64; d <<= 1) c += __shfl_xor(c, d);
    if (c >= TCAND) lo = mid; else hi = mid - 1;
  }
  const unsigned thr = lo;

  int cl = 0;
  #pragma unroll
  for (int i = 0; i < CAP / 64; ++i)
    cl += (int)((lane + 64 * i < n) && ((ck[i] >> 16) >= thr));
  int pre = cl;
  #pragma unroll
  for (int d = 1; d < 64; d <<= 1) {
    int y = __shfl_up(pre, d);
    if (lane >= d) pre += y;
  }
  const int total = __shfl(pre, 63);
  const int nc = total < CCAP ? total : CCAP;
  int slot = pre - cl;
  #pragma unroll
  for (int i = 0; i < CAP / 64; ++i) {
    if ((lane + 64 * i < n) && ((ck[i] >> 16) >= thr)) {
      if (slot < CCAP) scand[wv][slot] = ck[i];
      ++slot;
    }
  }
  __syncthreads();

  // fp64 rescore, candidates lane and lane+64 (verified R2 math)
  const double* arow = hn64 + (size_t)row * DD;
  double rv0 = -1.0e300, rv1 = -1.0e300;
  int rc0 = 0x7fffffff, rc1 = 0x7fffffff;
  if (lane < nc) {
    const int col = (int)(scand[wv][lane] & 0xFFFFu);
    const double* brow = hn64 + (size_t)col * DD;
    double acc = 0.0;
    for (int k = 0; k < DD; k += 2) {
      double2 a2 = *(const double2*)(arow + k);
      double2 b2 = *(const double2*)(brow + k);
      acc = fma(a2.x, b2.x, acc);
      acc = fma(a2.y, b2.y, acc);
    }
    rv0 = acc; rc0 = col;
  }
  if (lane + 64 < nc) {
    const int col = (int)(scand[wv][lane + 64] & 0xFFFFu);
    const double* brow = hn64 + (size_t)col * DD;
    double acc = 0.0;
    for (int k = 0; k < DD; k += 2) {
      double2 a2 = *(const double2*)(arow + k);
      double2 b2 = *(const double2*)(brow + k);
      acc = fma(a2.x, b2.x, acc);
      acc = fma(a2.y, b2.y, acc);
    }
    rv1 = acc; rc1 = col;
  }

  for (int itk = 0; itk < KTOP; ++itk) {
    bool f = (rv0 > rv1) || (rv0 == rv1 && rc0 < rc1);
    double bv = f ? rv0 : rv1;
    int bc = f ? rc0 : rc1;
    #pragma unroll
    for (int d = 1; d < 64; d <<= 1) {
      double ov = __shfl_xor(bv, d);
      int    oc = __shfl_xor(bc, d);
      bool tk = (ov > bv) || (ov == bv && oc < bc);
      bv = tk ? ov : bv;
      bc = tk ? oc : bc;
    }
    if (lane == itk) {
      resval[(size_t)row * KTOP + itk] = (float)fmax(bv, 0.0);
      rescol[(size_t)row * KTOP + itk] = bc;
    }
    if (rv0 == bv && rc0 == bc) rv0 = -1.0e300;
    else if (rv1 == bv && rc1 == bc) rv1 = -1.0e300;
  }
}

// ---------------- Kernel 5: emit full output rows (zeros + 31 scattered values) ----------------
__global__ __launch_bounds__(256)
void emit_kernel(const float* __restrict__ resval, const int* __restrict__ rescol,
                 float* __restrict__ out) {
  const int row = blockIdx.x, t = threadIdx.x;
  float v = 0.0f; int c = 0;
  if (t < KTOP) {
    v = resval[(size_t)row * KTOP + t];
    c = rescol[(size_t)row * KTOP + t];
  }
  float4* orow = (float4*)(out + (size_t)row * NN);
  const float4 z = {0.0f, 0.0f, 0.0f, 0.0f};
  #pragma unroll
  for (int i = 0; i < NN / 4 / 256; ++i)
    orow[i * 256 + t] = z;
  __syncthreads();   // zeros drained before scatter overwrites
  if (t < KTOP) out[(size_t)row * NN + c] = v;
}

extern "C" void kernel_launch(void* const* d_in, const int* in_sizes, int n_in,
                              void* d_out, int out_size, void* d_ws, size_t ws_size,
                              hipStream_t stream) {
  const float* feat = (const float*)d_in[0];
  const float* W1 = (const float*)d_in[1];
  const float* b1 = (const float*)d_in[2];
  const float* W2 = (const float*)d_in[3];
  const float* b2 = (const float*)d_in[4];
  float* out = (float*)d_out;

  // ws: hn64 12.6MB | hnb 3.1MB | resval 1.5MB | rescol 1.5MB | cand 75.5MB | cnt 48KB | tau 24KB
  double* hn64 = (double*)d_ws;
  unsigned short* hnb = (unsigned short*)(hn64 + (size_t)NN * DD);
  float* resval = (float*)(hnb + (size_t)NN * DD);
  int* rescol = (int*)(resval + (size_t)NN * KTOP);
  unsigned* cand = (unsigned*)(rescol + (size_t)NN * KTOP);
  int* cnt = (int*)(cand + (size_t)NN * CAP);
  unsigned short* tau = (unsigned short*)(cnt + NN);

  hipMemsetAsync(cnt, 0, NN * sizeof(int), stream);
  mlp_norm_kernel<<<NN / 8, 128, 0, stream>>>(feat, W1, b1, W2, b2, hn64, hnb);
  tau_kernel<<<NN / 4, 256, 0, stream>>>(hnb, tau);
  gemm_filter_kernel<<<GB * GB, 256, 0, stream>>>(hnb, tau, cnt, cand);
  rescore_kernel<<<NN / 4, 256, 0, stream>>>(cand, cnt, hn64, resval, rescol);
  emit_kernel<<<NN, 256, 0, stream>>>(resval, rescol, out);
}

// Round 8
// 1394.909 us; speedup vs baseline: 1.7226x; 1.7226x over previous
//
#include <hip/hip_runtime.h>
#include <stdint.h>
#include <math.h>

#define NN 12288
#define DD 128
#define KTOP 31
#define TILE 128
#define RB (NN / TILE)    // 96 row tiles
#define NCH 4             // col chunks (one owner block per (row,chunk))
#define CHC (NN / NCH)    // 3072 cols per chunk
#define NT (CHC / TILE)   // 24 col tiles per block
#define TCAND 64          // verified: top-64 by bf16 key, bucket-inclusive
#define CCAP 128          // compaction capacity (R6/R7-verified)
#define CAPC 384          // per-(row,chunk) candidate capacity (~16 sigma over expected ~170)
#define CAPT (NCH * CAPC) // 1536 total slots per row
#define TAURANK 24        // tau = 24th largest of 512-col sample, minus one bucket

typedef __attribute__((ext_vector_type(8))) short bf16x8;
typedef __attribute__((ext_vector_type(4))) float f32x4;

__device__ __forceinline__ unsigned short f2bf(float x) {  // RNE, no NaN in our data
  unsigned int u = __float_as_uint(x);
  u += 0x7fffu + ((u >> 16) & 1u);
  return (unsigned short)(u >> 16);
}
__device__ __forceinline__ float bf2f(unsigned int us) {
  return __uint_as_float((us & 0xFFFFu) << 16);
}

// ---------------- Kernel 1: MLP (Linear-ReLU-Linear) + L2 normalize, fp64; taps fp64 + bf16 ----------------
__global__ __launch_bounds__(128)
void mlp_norm_kernel(const float* __restrict__ feat,
                     const float* __restrict__ W1, const float* __restrict__ b1,
                     const float* __restrict__ W2, const float* __restrict__ b2,
                     double* __restrict__ hn64, unsigned short* __restrict__ hnb) {
  __shared__ double bufA[8][DD];
  __shared__ double bufB[8][DD];
  __shared__ double mnorm[8];
  const int t = threadIdx.x;
  const int row0 = blockIdx.x * 8;

  #pragma unroll
  for (int rr = 0; rr < 8; ++rr)
    bufA[rr][t] = (double)feat[(size_t)(row0 + rr) * DD + t];
  __syncthreads();

  {
    double acc[8] = {0,0,0,0,0,0,0,0};
    const float* wrow = W1 + (size_t)t * DD;
    for (int k = 0; k < DD; ++k) {
      double w = (double)wrow[k];
      #pragma unroll
      for (int rr = 0; rr < 8; ++rr)
        acc[rr] = fma(w, bufA[rr][k], acc[rr]);
    }
    double bb = (double)b1[t];
    #pragma unroll
    for (int rr = 0; rr < 8; ++rr)
      bufB[rr][t] = fmax(acc[rr] + bb, 0.0);
  }
  __syncthreads();
  {
    double acc[8] = {0,0,0,0,0,0,0,0};
    const float* wrow = W2 + (size_t)t * DD;
    for (int k = 0; k < DD; ++k) {
      double w = (double)wrow[k];
      #pragma unroll
      for (int rr = 0; rr < 8; ++rr)
        acc[rr] = fma(w, bufB[rr][k], acc[rr]);
    }
    double bb = (double)b2[t];
    #pragma unroll
    for (int rr = 0; rr < 8; ++rr)
      bufA[rr][t] = acc[rr] + bb;
  }
  __syncthreads();

  const int lane = t & 63;
  const int w = t >> 6;
  #pragma unroll
  for (int r2 = 0; r2 < 4; ++r2) {
    int rr = w * 4 + r2;
    double x0 = bufA[rr][lane];
    double x1 = bufA[rr][lane + 64];
    double s = x0 * x0 + x1 * x1;
    #pragma unroll
    for (int d = 1; d < 64; d <<= 1)
      s += __shfl_xor(s, d);
    if (lane == 0) mnorm[rr] = fmax(sqrt(s), 1e-12);
  }
  __syncthreads();
  #pragma unroll
  for (int rr = 0; rr < 8; ++rr) {
    double v = bufA[rr][t] / mnorm[rr];
    hn64[(size_t)(row0 + rr) * DD + t] = v;
    hnb[(size_t)(row0 + rr) * DD + t] = f2bf((float)v);
  }
}

// ---------------- Kernel 2: per-row tau from 512-col sample (R7-verified) ----------------
__global__ __launch_bounds__(256)
void tau_kernel(const unsigned short* __restrict__ hnb,
                unsigned short* __restrict__ tau) {
  __shared__ unsigned short rowbuf[4 * DD];
  const int t = threadIdx.x, lane = t & 63, wv = t >> 6;
  const int row0 = blockIdx.x * 4;
  ((unsigned*)rowbuf)[t] = ((const unsigned*)(hnb + (size_t)row0 * DD))[t];
  __syncthreads();
  const unsigned short* rb = rowbuf + wv * DD;

  float acc[8] = {0,0,0,0,0,0,0,0};
  for (int k8 = 0; k8 < DD; k8 += 8) {
    float rv[8];
    #pragma unroll
    for (int e = 0; e < 8; ++e) rv[e] = bf2f(rb[k8 + e]);
    #pragma unroll
    for (int s = 0; s < 8; ++s) {
      uint4 cv = *(const uint4*)(hnb + (size_t)(lane + 64 * s) * DD + k8);
      unsigned wd[4] = {cv.x, cv.y, cv.z, cv.w};
      #pragma unroll
      for (int q = 0; q < 4; ++q) {
        acc[s] = fmaf(bf2f(wd[q]), rv[2 * q], acc[s]);
        acc[s] = fmaf(bf2f(wd[q] >> 16), rv[2 * q + 1], acc[s]);
      }
    }
  }
  unsigned key[8];
  #pragma unroll
  for (int s = 0; s < 8; ++s) {
    unsigned bf = f2bf(acc[s]);
    key[s] = (bf & 0x8000u) ? 0u : bf;
  }
  unsigned lo = 0, hi = 0xFFFFu;
  while (lo < hi) {
    unsigned mid = (lo + hi + 1) >> 1;
    int c = 0;
    #pragma unroll
    for (int s = 0; s < 8; ++s) c += (int)(key[s] >= mid);
    #pragma unroll
    for (int d = 1; d < 64; d <<= 1) c += __shfl_xor(c, d);
    if (c >= TAURANK) lo = mid; else hi = mid - 1;
  }
  if (lane == 0) tau[row0 + wv] = (unsigned short)(lo ? lo - 1 : 0);
}

// ---------------- Kernel 3: MFMA GEMM + tau filter; LDS slot counters, owned segments ----------------
// grid = RB * NCH. Block (rowtile, chunk) owns cand[row][chunk][*] for its 128
// rows — slot via LDS atomicAdd, candidate via plain global store. NO global
// atomics (R7's 1300us lesson).
__device__ __forceinline__ int lunit(int c, int r, int q) {
  return c * 512 + r * 4 + ((q + (r >> 1)) & 3);
}

__global__ __launch_bounds__(256)
void gemm_filter_kernel(const unsigned short* __restrict__ hnb,
                        const unsigned short* __restrict__ tau,
                        int* __restrict__ cnt, unsigned* __restrict__ cand) {
  __shared__ __attribute__((aligned(16))) unsigned short At[16384];  // 32 KB
  __shared__ __attribute__((aligned(16))) unsigned short Bt[16384];  // 32 KB
  __shared__ int lcnt[TILE];
  const int t = threadIdx.x;
  const int lane = t & 63;
  const int wv = t >> 6;
  const int rowtile = blockIdx.x >> 2, chunk = blockIdx.x & 3;
  const int r0 = rowtile * TILE;
  const int cbase = chunk * CHC;

  // stage A tile once (verified swizzle staging)
  #pragma unroll
  for (int i = 0; i < 8; ++i) {
    int u = i * 256 + t;
    int c = u >> 9, r = (u >> 2) & 127, g = u & 3;
    int q = (g - (r >> 1)) & 3;
    uint4 v = *(const uint4*)(hnb + (size_t)(r0 + r) * DD + c * 32 + q * 8);
    *(uint4*)(At + u * 8) = v;
  }
  if (t < TILE) lcnt[t] = 0;

  const int wr = (wv >> 1) * 64;
  const int wc = (wv & 1) * 64;
  const int m = lane & 15, quad = lane >> 4;

  // hoist this lane's 16 row taus + row ids + cand segment bases
  unsigned short tr[4][4];
  #pragma unroll
  for (int i = 0; i < 4; ++i)
    #pragma unroll
    for (int r = 0; r < 4; ++r)
      tr[i][r] = tau[r0 + wr + i * 16 + quad * 4 + r];

  for (int tile = 0; tile < NT; ++tile) {
    __syncthreads();   // prev tile's MFMA reads + epilogue done
    const int c0t = cbase + tile * TILE;
    #pragma unroll
    for (int i = 0; i < 8; ++i) {
      int u = i * 256 + t;
      int c = u >> 9, r = (u >> 2) & 127, g = u & 3;
      int q = (g - (r >> 1)) & 3;
      uint4 v = *(const uint4*)(hnb + (size_t)(c0t + r) * DD + c * 32 + q * 8);
      *(uint4*)(Bt + u * 8) = v;
    }
    __syncthreads();

    f32x4 acc[4][4] = {};
    #pragma unroll
    for (int kc = 0; kc < 4; ++kc) {
      bf16x8 a[4], b[4];
      #pragma unroll
      for (int i = 0; i < 4; ++i)
        a[i] = *(const bf16x8*)(At + lunit(kc, wr + i * 16 + m, quad) * 8);
      #pragma unroll
      for (int j = 0; j < 4; ++j)
        b[j] = *(const bf16x8*)(Bt + lunit(kc, wc + j * 16 + m, quad) * 8);
      #pragma unroll
      for (int i = 0; i < 4; ++i)
        #pragma unroll
        for (int j = 0; j < 4; ++j)
          acc[i][j] = __builtin_amdgcn_mfma_f32_16x16x32_bf16(a[i], b[j], acc[i][j], 0, 0, 0);
    }

    // filter epilogue: LDS slot reservation + plain global store to owned segment
    #pragma unroll
    for (int i = 0; i < 4; ++i)
      #pragma unroll
      for (int r = 0; r < 4; ++r) {
        const int Rl = wr + i * 16 + quad * 4 + r;
        const unsigned tv = tr[i][r];
        #pragma unroll
        for (int j = 0; j < 4; ++j) {
          float v = acc[i][j][r];
          unsigned bf = f2bf(v);
          unsigned key = (bf & 0x8000u) ? 0u : bf;
          if (key >= tv) {
            int slot = atomicAdd(&lcnt[Rl], 1);
            int C = c0t + wc + j * 16 + m;
            if (slot < CAPC)
              cand[((size_t)(r0 + Rl) * NCH + chunk) * CAPC + slot] =
                  (key << 16) | (unsigned)C;
          }
        }
      }
  }

  __syncthreads();
  if (t < TILE) cnt[(r0 + t) * NCH + chunk] = lcnt[t];
}

// ---------------- Kernel 4: candidate select (R6/R7-verified semantics) + fp64 rescore ----------------
__global__ __launch_bounds__(256)
void rescore_kernel(const unsigned* __restrict__ cand, const int* __restrict__ cnt,
                    const double* __restrict__ hn64,
                    float* __restrict__ resval, int* __restrict__ rescol) {
  __shared__ unsigned scand[4][CCAP];
  const int t = threadIdx.x, lane = t & 63, wv = t >> 6;
  const int row = blockIdx.x * 4 + wv;

  int nseg[NCH];
  #pragma unroll
  for (int s = 0; s < NCH; ++s) {
    int n = cnt[row * NCH + s];
    nseg[s] = n > CAPC ? CAPC : n;
  }
  const unsigned* crow = cand + (size_t)row * CAPT;

  unsigned ck[CAPT / 64];
  bool vl[CAPT / 64];
  #pragma unroll
  for (int i = 0; i < CAPT / 64; ++i) {
    int idx = lane + 64 * i;
    int seg = idx / CAPC, slot = idx - seg * CAPC;
    bool v = slot < nseg[seg];
    vl[i] = v;
    ck[i] = v ? crow[idx] : 0u;
  }

  unsigned lo = 0, hi = 0xFFFFu;
  while (lo < hi) {
    unsigned mid = (lo + hi + 1) >> 1;
    int c = 0;
    #pragma unroll
    for (int i = 0; i < CAPT / 64; ++i) c += (int)((ck[i] >> 16) >= mid);
    #pragma unroll
    for (int d = 1; d < 64; d <<= 1) c += __shfl_xor(c, d);
    if (c >= TCAND) lo = mid; else hi = mid - 1;
  }
  const unsigned thr = lo;

  int cl = 0;
  #pragma unroll
  for (int i = 0; i < CAPT / 64; ++i)
    cl += (int)(vl[i] && ((ck[i] >> 16) >= thr));
  int pre = cl;
  #pragma unroll
  for (int d = 1; d < 64; d <<= 1) {
    int y = __shfl_up(pre, d);
    if (lane >= d) pre += y;
  }
  const int total = __shfl(pre, 63);
  const int nc = total < CCAP ? total : CCAP;
  int slot = pre - cl;
  #pragma unroll
  for (int i = 0; i < CAPT / 64; ++i) {
    if (vl[i] && ((ck[i] >> 16) >= thr)) {
      if (slot < CCAP) scand[wv][slot] = ck[i];
      ++slot;
    }
  }
  __syncthreads();

  // fp64 rescore, candidates lane and lane+64 (verified R2 math)
  const double* arow = hn64 + (size_t)row * DD;
  double rv0 = -1.0e300, rv1 = -1.0e300;
  int rc0 = 0x7fffffff, rc1 = 0x7fffffff;
  if (lane < nc) {
    const int col = (int)(scand[wv][lane] & 0xFFFFu);
    const double* brow = hn64 + (size_t)col * DD;
    double acc = 0.0;
    for (int k = 0; k < DD; k += 2) {
      double2 a2 = *(const double2*)(arow + k);
      double2 b2 = *(const double2*)(brow + k);
      acc = fma(a2.x, b2.x, acc);
      acc = fma(a2.y, b2.y, acc);
    }
    rv0 = acc; rc0 = col;
  }
  if (lane + 64 < nc) {
    const int col = (int)(scand[wv][lane + 64] & 0xFFFFu);
    const double* brow = hn64 + (size_t)col * DD;
    double acc = 0.0;
    for (int k = 0; k < DD; k += 2) {
      double2 a2 = *(const double2*)(arow + k);
      double2 b2 = *(const double2*)(brow + k);
      acc = fma(a2.x, b2.x, acc);
      acc = fma(a2.y, b2.y, acc);
    }
    rv1 = acc; rc1 = col;
  }

  for (int itk = 0; itk < KTOP; ++itk) {
    bool f = (rv0 > rv1) || (rv0 == rv1 && rc0 < rc1);
    double bv = f ? rv0 : rv1;
    int bc = f ? rc0 : rc1;
    #pragma unroll
    for (int d = 1; d < 64; d <<= 1) {
      double ov = __shfl_xor(bv, d);
      int    oc = __shfl_xor(bc, d);
      bool tk = (ov > bv) || (ov == bv && oc < bc);
      bv = tk ? ov : bv;
      bc = tk ? oc : bc;
    }
    if (lane == itk) {
      resval[(size_t)row * KTOP + itk] = (float)fmax(bv, 0.0);
      rescol[(size_t)row * KTOP + itk] = bc;
    }
    if (rv0 == bv && rc0 == bc) rv0 = -1.0e300;
    else if (rv1 == bv && rc1 == bc) rv1 = -1.0e300;
  }
}

// ---------------- Kernel 5: emit full output rows (zeros + 31 scattered values) ----------------
__global__ __launch_bounds__(256)
void emit_kernel(const float* __restrict__ resval, const int* __restrict__ rescol,
                 float* __restrict__ out) {
  const int row = blockIdx.x, t = threadIdx.x;
  float v = 0.0f; int c = 0;
  if (t < KTOP) {
    v = resval[(size_t)row * KTOP + t];
    c = rescol[(size_t)row * KTOP + t];
  }
  float4* orow = (float4*)(out + (size_t)row * NN);
  const float4 z = {0.0f, 0.0f, 0.0f, 0.0f};
  #pragma unroll
  for (int i = 0; i < NN / 4 / 256; ++i)
    orow[i * 256 + t] = z;
  __syncthreads();   // zeros drained before scatter overwrites
  if (t < KTOP) out[(size_t)row * NN + c] = v;
}

extern "C" void kernel_launch(void* const* d_in, const int* in_sizes, int n_in,
                              void* d_out, int out_size, void* d_ws, size_t ws_size,
                              hipStream_t stream) {
  const float* feat = (const float*)d_in[0];
  const float* W1 = (const float*)d_in[1];
  const float* b1 = (const float*)d_in[2];
  const float* W2 = (const float*)d_in[3];
  const float* b2 = (const float*)d_in[4];
  float* out = (float*)d_out;

  // ws: hn64 12.6MB | hnb 3.1MB | resval 1.5MB | rescol 1.5MB | cand 75.5MB | cnt 192KB | tau 24KB
  double* hn64 = (double*)d_ws;
  unsigned short* hnb = (unsigned short*)(hn64 + (size_t)NN * DD);
  float* resval = (float*)(hnb + (size_t)NN * DD);
  int* rescol = (int*)(resval + (size_t)NN * KTOP);
  unsigned* cand = (unsigned*)(rescol + (size_t)NN * KTOP);
  int* cnt = (int*)(cand + (size_t)NN * CAPT);
  unsigned short* tau = (unsigned short*)(cnt + NN * NCH);

  mlp_norm_kernel<<<NN / 8, 128, 0, stream>>>(feat, W1, b1, W2, b2, hn64, hnb);
  tau_kernel<<<NN / 4, 256, 0, stream>>>(hnb, tau);
  gemm_filter_kernel<<<RB * NCH, 256, 0, stream>>>(hnb, tau, cnt, cand);
  rescore_kernel<<<NN / 4, 256, 0, stream>>>(cand, cnt, hn64, resval, rescol);
  emit_kernel<<<NN, 256, 0, stream>>>(resval, rescol, out);
}

// Round 9
// 1094.576 us; speedup vs baseline: 2.1952x; 1.2744x over previous
//
#include <hip/hip_runtime.h>
#include <stdint.h>
#include <math.h>

#define NN 12288
#define DD 128
#define KTOP 31
#define TILE 128
#define RB (NN / TILE)    // 96 row tiles
#define NCH 4             // col chunks (one owner block per (row,chunk))
#define CHC (NN / NCH)    // 3072 cols per chunk
#define NT (CHC / TILE)   // 24 col tiles per block
#define TCAND 64          // verified: top-64 by bf16 key, bucket-inclusive
#define CCAP 128          // compaction capacity (R6/R7/R8-verified)
#define CAPC 384          // per-(row,chunk) candidate capacity
#define CAPT (NCH * CAPC) // 1536 total slots per row
#define TAURANK 24        // tau = 24th largest of 512-col sample, minus one bucket
#define TROWS 16          // rows per tau block

typedef __attribute__((ext_vector_type(8))) short bf16x8;
typedef __attribute__((ext_vector_type(4))) float f32x4;

__device__ __forceinline__ unsigned short f2bf(float x) {  // RNE, no NaN in our data
  unsigned int u = __float_as_uint(x);
  u += 0x7fffu + ((u >> 16) & 1u);
  return (unsigned short)(u >> 16);
}
__device__ __forceinline__ float bf2f(unsigned int us) {
  return __uint_as_float((us & 0xFFFFu) << 16);
}

// ---------------- Kernel 1: MLP + L2 normalize, fp64 math (R2-verified ordering), float4 W loads ----------------
__global__ __launch_bounds__(128)
void mlp_norm_kernel(const float* __restrict__ feat,
                     const float* __restrict__ W1, const float* __restrict__ b1,
                     const float* __restrict__ W2, const float* __restrict__ b2,
                     double* __restrict__ hn64, unsigned short* __restrict__ hnb) {
  __shared__ double bufA[8][DD];
  __shared__ double bufB[8][DD];
  __shared__ double mnorm[8];
  const int t = threadIdx.x;
  const int row0 = blockIdx.x * 8;

  #pragma unroll
  for (int rr = 0; rr < 8; ++rr)
    bufA[rr][t] = (double)feat[(size_t)(row0 + rr) * DD + t];
  __syncthreads();

  {
    double acc[8] = {0,0,0,0,0,0,0,0};
    const float4* w4 = (const float4*)(W1 + (size_t)t * DD);
    for (int kk = 0; kk < DD / 4; ++kk) {
      float4 w = w4[kk];
      #pragma unroll
      for (int rr = 0; rr < 8; ++rr) {   // same k-ascending fp64 fma chain as R2
        acc[rr] = fma((double)w.x, bufA[rr][4*kk+0], acc[rr]);
        acc[rr] = fma((double)w.y, bufA[rr][4*kk+1], acc[rr]);
        acc[rr] = fma((double)w.z, bufA[rr][4*kk+2], acc[rr]);
        acc[rr] = fma((double)w.w, bufA[rr][4*kk+3], acc[rr]);
      }
    }
    double bb = (double)b1[t];
    #pragma unroll
    for (int rr = 0; rr < 8; ++rr)
      bufB[rr][t] = fmax(acc[rr] + bb, 0.0);
  }
  __syncthreads();
  {
    double acc[8] = {0,0,0,0,0,0,0,0};
    const float4* w4 = (const float4*)(W2 + (size_t)t * DD);
    for (int kk = 0; kk < DD / 4; ++kk) {
      float4 w = w4[kk];
      #pragma unroll
      for (int rr = 0; rr < 8; ++rr) {
        acc[rr] = fma((double)w.x, bufB[rr][4*kk+0], acc[rr]);
        acc[rr] = fma((double)w.y, bufB[rr][4*kk+1], acc[rr]);
        acc[rr] = fma((double)w.z, bufB[rr][4*kk+2], acc[rr]);
        acc[rr] = fma((double)w.w, bufB[rr][4*kk+3], acc[rr]);
      }
    }
    double bb = (double)b2[t];
    #pragma unroll
    for (int rr = 0; rr < 8; ++rr)
      bufA[rr][t] = acc[rr] + bb;
  }
  __syncthreads();

  const int lane = t & 63;
  const int w = t >> 6;
  #pragma unroll
  for (int r2 = 0; r2 < 4; ++r2) {
    int rr = w * 4 + r2;
    double x0 = bufA[rr][lane];
    double x1 = bufA[rr][lane + 64];
    double s = x0 * x0 + x1 * x1;
    #pragma unroll
    for (int d = 1; d < 64; d <<= 1)
      s += __shfl_xor(s, d);
    if (lane == 0) mnorm[rr] = fmax(sqrt(s), 1e-12);
  }
  __syncthreads();
  #pragma unroll
  for (int rr = 0; rr < 8; ++rr) {
    double v = bufA[rr][t] / mnorm[rr];
    hn64[(size_t)(row0 + rr) * DD + t] = v;
    hnb[(size_t)(row0 + rr) * DD + t] = f2bf((float)v);
  }
}

// ---------------- Kernel 2: per-row float threshold from 512-col sample ----------------
// 16 rows/block; sample chunk staged to LDS per k8 (kills the 64-line-split
// per-lane gathers of R7/R8). Same sample (cols 0..511), same TAURANK-minus-
// one-bucket tau as the verified R7/R8 path; emits float threshold
// T = midpoint(bf2f(tau-1), bf2f(tau)) s.t. {v: key(v) >= tau} subset of
// {v: v >= T} (RNE monotone; boundary ties only ADD candidates).
__global__ __launch_bounds__(256)
void tau_kernel(const unsigned short* __restrict__ hnb,
                float* __restrict__ tauf) {
  __shared__ unsigned short rowbuf[TROWS * DD];                           // 4 KB
  __shared__ __attribute__((aligned(16))) unsigned short sbuf[512 * 8];  // 8 KB
  const int t = threadIdx.x, lane = t & 63, wv = t >> 6;
  const int row0 = blockIdx.x * TROWS;

  #pragma unroll
  for (int i = 0; i < 4; ++i)
    ((unsigned*)rowbuf)[t + 256 * i] =
        ((const unsigned*)(hnb + (size_t)row0 * DD))[t + 256 * i];

  float acc[4][8];
  #pragma unroll
  for (int rr = 0; rr < 4; ++rr)
    #pragma unroll
    for (int s = 0; s < 8; ++s) acc[rr][s] = 0.0f;

  for (int k8 = 0; k8 < 16; ++k8) {
    __syncthreads();   // prev consume done (first iter: rowbuf visible too)
    ((uint4*)sbuf)[t]       = *(const uint4*)(hnb + (size_t)t * DD + k8 * 8);
    ((uint4*)sbuf)[t + 256] = *(const uint4*)(hnb + (size_t)(t + 256) * DD + k8 * 8);
    __syncthreads();

    float rv[4][8];
    #pragma unroll
    for (int rr = 0; rr < 4; ++rr)
      #pragma unroll
      for (int e2 = 0; e2 < 4; ++e2) {
        unsigned w = ((const unsigned*)rowbuf)[(wv * 4 + rr) * 64 + k8 * 4 + e2];
        rv[rr][2 * e2]     = bf2f(w);
        rv[rr][2 * e2 + 1] = bf2f(w >> 16);
      }
    #pragma unroll
    for (int s = 0; s < 8; ++s) {
      uint4 cv = *(const uint4*)(sbuf + (lane + 64 * s) * 8);
      unsigned wd[4] = {cv.x, cv.y, cv.z, cv.w};
      #pragma unroll
      for (int rr = 0; rr < 4; ++rr)
        #pragma unroll
        for (int q = 0; q < 4; ++q) {
          acc[rr][s] = fmaf(bf2f(wd[q]),       rv[rr][2 * q],     acc[rr][s]);
          acc[rr][s] = fmaf(bf2f(wd[q] >> 16), rv[rr][2 * q + 1], acc[rr][s]);
        }
    }
  }

  #pragma unroll
  for (int rr = 0; rr < 4; ++rr) {
    unsigned key[8];
    #pragma unroll
    for (int s = 0; s < 8; ++s) {
      unsigned bf = f2bf(acc[rr][s]);
      key[s] = (bf & 0x8000u) ? 0u : bf;
    }
    unsigned lo = 0, hi = 0xFFFFu;
    while (lo < hi) {
      unsigned mid = (lo + hi + 1) >> 1;
      int c = 0;
      #pragma unroll
      for (int s = 0; s < 8; ++s) c += (int)(key[s] >= mid);
      #pragma unroll
      for (int d = 1; d < 64; d <<= 1) c += __shfl_xor(c, d);
      if (c >= TAURANK) lo = mid; else hi = mid - 1;
    }
    if (lane == 0) {
      unsigned tl = lo ? lo - 1 : 0;  // minus one bucket (verified)
      tauf[row0 + wv * 4 + rr] = tl ? 0.5f * (bf2f(tl - 1) + bf2f(tl)) : -2.0f;
    }
  }
}

// ---------------- Kernel 3: MFMA GEMM + float-threshold filter; LDS counters, owned segments ----------------
__device__ __forceinline__ int lunit(int c, int r, int q) {
  return c * 512 + r * 4 + ((q + (r >> 1)) & 3);
}

__global__ __launch_bounds__(256)
void gemm_filter_kernel(const unsigned short* __restrict__ hnb,
                        const float* __restrict__ tauf,
                        int* __restrict__ cnt, unsigned* __restrict__ cand) {
  __shared__ __attribute__((aligned(16))) unsigned short At[16384];  // 32 KB
  __shared__ __attribute__((aligned(16))) unsigned short Bt[16384];  // 32 KB
  __shared__ int lcnt[TILE];
  const int t = threadIdx.x;
  const int lane = t & 63;
  const int wv = t >> 6;
  const int rowtile = blockIdx.x >> 2, chunk = blockIdx.x & 3;
  const int r0 = rowtile * TILE;
  const int cbase = chunk * CHC;

  #pragma unroll
  for (int i = 0; i < 8; ++i) {
    int u = i * 256 + t;
    int c = u >> 9, r = (u >> 2) & 127, g = u & 3;
    int q = (g - (r >> 1)) & 3;
    uint4 v = *(const uint4*)(hnb + (size_t)(r0 + r) * DD + c * 32 + q * 8);
    *(uint4*)(At + u * 8) = v;
  }
  if (t < TILE) lcnt[t] = 0;

  const int wr = (wv >> 1) * 64;
  const int wc = (wv & 1) * 64;
  const int m = lane & 15, quad = lane >> 4;

  float tr[4][4];
  #pragma unroll
  for (int i = 0; i < 4; ++i)
    #pragma unroll
    for (int r = 0; r < 4; ++r)
      tr[i][r] = tauf[r0 + wr + i * 16 + quad * 4 + r];

  for (int tile = 0; tile < NT; ++tile) {
    __syncthreads();
    const int c0t = cbase + tile * TILE;
    #pragma unroll
    for (int i = 0; i < 8; ++i) {
      int u = i * 256 + t;
      int c = u >> 9, r = (u >> 2) & 127, g = u & 3;
      int q = (g - (r >> 1)) & 3;
      uint4 v = *(const uint4*)(hnb + (size_t)(c0t + r) * DD + c * 32 + q * 8);
      *(uint4*)(Bt + u * 8) = v;
    }
    __syncthreads();

    f32x4 acc[4][4] = {};
    #pragma unroll
    for (int kc = 0; kc < 4; ++kc) {
      bf16x8 a[4], b[4];
      #pragma unroll
      for (int i = 0; i < 4; ++i)
        a[i] = *(const bf16x8*)(At + lunit(kc, wr + i * 16 + m, quad) * 8);
      #pragma unroll
      for (int j = 0; j < 4; ++j)
        b[j] = *(const bf16x8*)(Bt + lunit(kc, wc + j * 16 + m, quad) * 8);
      #pragma unroll
      for (int i = 0; i < 4; ++i)
        #pragma unroll
        for (int j = 0; j < 4; ++j)
          acc[i][j] = __builtin_amdgcn_mfma_f32_16x16x32_bf16(a[i], b[j], acc[i][j], 0, 0, 0);
    }

    // epilogue: max-gated float compare, LDS slot reservation, plain store
    #pragma unroll
    for (int i = 0; i < 4; ++i)
      #pragma unroll
      for (int r = 0; r < 4; ++r) {
        const int Rl = wr + i * 16 + quad * 4 + r;
        const float tv = tr[i][r];
        float m01 = fmaxf(acc[i][0][r], acc[i][1][r]);
        float m23 = fmaxf(acc[i][2][r], acc[i][3][r]);
        if (fmaxf(m01, m23) >= tv) {
          #pragma unroll
          for (int j = 0; j < 4; ++j) {
            float v = acc[i][j][r];
            if (v >= tv) {
              unsigned bf = f2bf(v);
              unsigned key = (bf & 0x8000u) ? 0u : bf;
              int slot = atomicAdd(&lcnt[Rl], 1);
              int C = c0t + wc + j * 16 + m;
              if (slot < CAPC)
                cand[((size_t)(r0 + Rl) * NCH + chunk) * CAPC + slot] =
                    (key << 16) | (unsigned)C;
            }
          }
        }
      }
  }

  __syncthreads();
  if (t < TILE) cnt[(r0 + t) * NCH + chunk] = lcnt[t];
}

// ---------------- Kernel 4: candidate select (verified semantics) + cooperative fp64 rescore ----------------
__global__ __launch_bounds__(256)
void rescore_kernel(const unsigned* __restrict__ cand, const int* __restrict__ cnt,
                    const double* __restrict__ hn64,
                    float* __restrict__ resval, int* __restrict__ rescol) {
  __shared__ unsigned scand[4][CCAP];
  const int t = threadIdx.x, lane = t & 63, wv = t >> 6;
  const int row = blockIdx.x * 4 + wv;

  int nseg[NCH];
  #pragma unroll
  for (int s = 0; s < NCH; ++s) {
    int n = cnt[row * NCH + s];
    nseg[s] = n > CAPC ? CAPC : n;
  }
  const unsigned* crow = cand + (size_t)row * CAPT;

  unsigned ck[CAPT / 64];
  bool vl[CAPT / 64];
  #pragma unroll
  for (int i = 0; i < CAPT / 64; ++i) {
    int idx = lane + 64 * i;
    int seg = idx / CAPC, slot = idx - seg * CAPC;
    bool v = slot < nseg[seg];
    vl[i] = v;
    ck[i] = v ? crow[idx] : 0u;
  }

  unsigned lo = 0, hi = 0xFFFFu;
  while (lo < hi) {
    unsigned mid = (lo + hi + 1) >> 1;
    int c = 0;
    #pragma unroll
    for (int i = 0; i < CAPT / 64; ++i) c += (int)((ck[i] >> 16) >= mid);
    #pragma unroll
    for (int d = 1; d < 64; d <<= 1) c += __shfl_xor(c, d);
    if (c >= TCAND) lo = mid; else hi = mid - 1;
  }
  const unsigned thr = lo;

  int cl = 0;
  #pragma unroll
  for (int i = 0; i < CAPT / 64; ++i)
    cl += (int)(vl[i] && ((ck[i] >> 16) >= thr));
  int pre = cl;
  #pragma unroll
  for (int d = 1; d < 64; d <<= 1) {
    int y = __shfl_up(pre, d);
    if (lane >= d) pre += y;
  }
  const int total = __shfl(pre, 63);
  const int nc = total < CCAP ? total : CCAP;
  int slot = pre - cl;
  #pragma unroll
  for (int i = 0; i < CAPT / 64; ++i) {
    if (vl[i] && ((ck[i] >> 16) >= thr)) {
      if (slot < CCAP) scand[wv][slot] = ck[i];
      ++slot;
    }
  }
  __syncthreads();

  // cooperative fp64 rescore: all 64 lanes dot one candidate (coalesced 1KB
  // row read), 4 candidates in flight; result parked at lane cc&63, reg cc>>6.
  // fp64 summation-order differs from R2's sequential chain but fp64 noise
  // (~1e-15) << rank gaps (~1e-3) -> selection invariant.
  const double2 a2 = *(const double2*)(hn64 + (size_t)row * DD + 2 * lane);
  double rv0 = -1.0e300, rv1 = -1.0e300;
  int rc0 = 0x7fffffff, rc1 = 0x7fffffff;
  for (int c = 0; c < nc; c += 4) {
    double p[4]; int cols[4];
    #pragma unroll
    for (int u = 0; u < 4; ++u) {
      int cc = c + u;
      int ccl = cc < nc ? cc : nc - 1;
      int col = (int)(scand[wv][ccl] & 0xFFFFu);
      cols[u] = col;
      double2 b2 = *(const double2*)(hn64 + (size_t)col * DD + 2 * lane);
      p[u] = fma(a2.x, b2.x, a2.y * b2.y);
    }
    #pragma unroll
    for (int d = 1; d < 64; d <<= 1)
      #pragma unroll
      for (int u = 0; u < 4; ++u) p[u] += __shfl_xor(p[u], d);
    #pragma unroll
    for (int u = 0; u < 4; ++u) {
      int cc = c + u;
      if (cc < nc && (cc & 63) == lane) {
        if (cc < 64) { rv0 = p[u]; rc0 = cols[u]; }
        else         { rv1 = p[u]; rc1 = cols[u]; }
      }
    }
  }

  for (int itk = 0; itk < KTOP; ++itk) {
    bool f = (rv0 > rv1) || (rv0 == rv1 && rc0 < rc1);
    double bv = f ? rv0 : rv1;
    int bc = f ? rc0 : rc1;
    #pragma unroll
    for (int d = 1; d < 64; d <<= 1) {
      double ov = __shfl_xor(bv, d);
      int    oc = __shfl_xor(bc, d);
      bool tk = (ov > bv) || (ov == bv && oc < bc);
      bv = tk ? ov : bv;
      bc = tk ? oc : bc;
    }
    if (lane == itk) {
      resval[(size_t)row * KTOP + itk] = (float)fmax(bv, 0.0);
      rescol[(size_t)row * KTOP + itk] = bc;
    }
    if (rv0 == bv && rc0 == bc) rv0 = -1.0e300;
    else if (rv1 == bv && rc1 == bc) rv1 = -1.0e300;
  }
}

// ---------------- Kernel 5: emit full output rows (zeros + 31 scattered values) ----------------
__global__ __launch_bounds__(256)
void emit_kernel(const float* __restrict__ resval, const int* __restrict__ rescol,
                 float* __restrict__ out) {
  const int row = blockIdx.x, t = threadIdx.x;
  float v = 0.0f; int c = 0;
  if (t < KTOP) {
    v = resval[(size_t)row * KTOP + t];
    c = rescol[(size_t)row * KTOP + t];
  }
  float4* orow = (float4*)(out + (size_t)row * NN);
  const float4 z = {0.0f, 0.0f, 0.0f, 0.0f};
  #pragma unroll
  for (int i = 0; i < NN / 4 / 256; ++i)
    orow[i * 256 + t] = z;
  __syncthreads();   // zeros drained before scatter overwrites
  if (t < KTOP) out[(size_t)row * NN + c] = v;
}

extern "C" void kernel_launch(void* const* d_in, const int* in_sizes, int n_in,
                              void* d_out, int out_size, void* d_ws, size_t ws_size,
                              hipStream_t stream) {
  const float* feat = (const float*)d_in[0];
  const float* W1 = (const float*)d_in[1];
  const float* b1 = (const float*)d_in[2];
  const float* W2 = (const float*)d_in[3];
  const float* b2 = (const float*)d_in[4];
  float* out = (float*)d_out;

  // ws: hn64 12.6MB | hnb 3.1MB | resval 1.5MB | rescol 1.5MB | cand 75.5MB | cnt 192KB | tauf 48KB
  double* hn64 = (double*)d_ws;
  unsigned short* hnb = (unsigned short*)(hn64 + (size_t)NN * DD);
  float* resval = (float*)(hnb + (size_t)NN * DD);
  int* rescol = (int*)(resval + (size_t)NN * KTOP);
  unsigned* cand = (unsigned*)(rescol + (size_t)NN * KTOP);
  int* cnt = (int*)(cand + (size_t)NN * CAPT);
  float* tauf = (float*)(cnt + NN * NCH);

  mlp_norm_kernel<<<NN / 8, 128, 0, stream>>>(feat, W1, b1, W2, b2, hn64, hnb);
  tau_kernel<<<NN / TROWS, 256, 0, stream>>>(hnb, tauf);
  gemm_filter_kernel<<<RB * NCH, 256, 0, stream>>>(hnb, tauf, cnt, cand);
  rescore_kernel<<<NN / 4, 256, 0, stream>>>(cand, cnt, hn64, resval, rescol);
  emit_kernel<<<NN, 256, 0, stream>>>(resval, rescol, out);
}

// Round 11
// 1068.197 us; speedup vs baseline: 2.2495x; 1.0247x over previous
//
#include <hip/hip_runtime.h>
#include <stdint.h>
#include <math.h>

#define NN 12288
#define DD 128
#define KTOP 31
#define TILE 128
#define RB (NN / TILE)    // 96 row tiles
#define NCH 4             // col chunks (R8/R9-verified capacity geometry)
#define CHC (NN / NCH)    // 3072 cols per chunk
#define NT (CHC / TILE)   // 24 col tiles per block
#define TCAND 64          // verified: top-64 by bf16 key, bucket-inclusive
#define CCAP 128          // compaction capacity (R6..R9-verified)
#define CAPC 384          // per-(row,chunk) capacity (R8/R9-verified, ~15 sigma)
#define CAPT (NCH * CAPC) // 1536 total slots per row
#define TAURANK 24        // tau = 24th largest of 512-col sample, minus one bucket
#define TROWS 16          // rows per tau block

typedef __attribute__((ext_vector_type(8))) short bf16x8;
typedef __attribute__((ext_vector_type(4))) float f32x4;

__device__ __forceinline__ unsigned short f2bf(float x) {  // RNE, no NaN in our data
  unsigned int u = __float_as_uint(x);
  u += 0x7fffu + ((u >> 16) & 1u);
  return (unsigned short)(u >> 16);
}
__device__ __forceinline__ float bf2f(unsigned int us) {
  return __uint_as_float((us & 0xFFFFu) << 16);
}

// ---------------- Kernel 1: MLP + L2 normalize (fp64, R2-verified ordering) ----------------
// Outputs hn64, hnb (linear, for tau), hnbs (pre-swizzled 128-row tile images;
// unit u = c*512 + r*4 + g holds row r, k in [c*32 + q*8, +8), q=(g-(r>>1))&3
// — exactly the R9-verified LDS staging layout).
__global__ __launch_bounds__(128)
void mlp_norm_kernel(const float* __restrict__ feat,
                     const float* __restrict__ W1, const float* __restrict__ b1,
                     const float* __restrict__ W2, const float* __restrict__ b2,
                     double* __restrict__ hn64, unsigned short* __restrict__ hnb,
                     uint4* __restrict__ hnbs) {
  __shared__ double bufA[8][DD];
  __shared__ double bufB[8][DD];
  __shared__ double mnorm[8];
  __shared__ __attribute__((aligned(16))) unsigned short rowb[8][DD];
  const int t = threadIdx.x;
  const int row0 = blockIdx.x * 8;

  #pragma unroll
  for (int rr = 0; rr < 8; ++rr)
    bufA[rr][t] = (double)feat[(size_t)(row0 + rr) * DD + t];
  __syncthreads();

  {
    double acc[8] = {0,0,0,0,0,0,0,0};
    const float4* w4 = (const float4*)(W1 + (size_t)t * DD);
    for (int kk = 0; kk < DD / 4; ++kk) {
      float4 w = w4[kk];
      #pragma unroll
      for (int rr = 0; rr < 8; ++rr) {   // k-ascending fp64 fma chain (R2-verified)
        acc[rr] = fma((double)w.x, bufA[rr][4*kk+0], acc[rr]);
        acc[rr] = fma((double)w.y, bufA[rr][4*kk+1], acc[rr]);
        acc[rr] = fma((double)w.z, bufA[rr][4*kk+2], acc[rr]);
        acc[rr] = fma((double)w.w, bufA[rr][4*kk+3], acc[rr]);
      }
    }
    double bb = (double)b1[t];
    #pragma unroll
    for (int rr = 0; rr < 8; ++rr)
      bufB[rr][t] = fmax(acc[rr] + bb, 0.0);
  }
  __syncthreads();
  {
    double acc[8] = {0,0,0,0,0,0,0,0};
    const float4* w4 = (const float4*)(W2 + (size_t)t * DD);
    for (int kk = 0; kk < DD / 4; ++kk) {
      float4 w = w4[kk];
      #pragma unroll
      for (int rr = 0; rr < 8; ++rr) {
        acc[rr] = fma((double)w.x, bufB[rr][4*kk+0], acc[rr]);
        acc[rr] = fma((double)w.y, bufB[rr][4*kk+1], acc[rr]);
        acc[rr] = fma((double)w.z, bufB[rr][4*kk+2], acc[rr]);
        acc[rr] = fma((double)w.w, bufB[rr][4*kk+3], acc[rr]);
      }
    }
    double bb = (double)b2[t];
    #pragma unroll
    for (int rr = 0; rr < 8; ++rr)
      bufA[rr][t] = acc[rr] + bb;
  }
  __syncthreads();

  const int lane = t & 63;
  const int w = t >> 6;
  #pragma unroll
  for (int r2 = 0; r2 < 4; ++r2) {
    int rr = w * 4 + r2;
    double x0 = bufA[rr][lane];
    double x1 = bufA[rr][lane + 64];
    double s = x0 * x0 + x1 * x1;
    #pragma unroll
    for (int d = 1; d < 64; d <<= 1)
      s += __shfl_xor(s, d);
    if (lane == 0) mnorm[rr] = fmax(sqrt(s), 1e-12);
  }
  __syncthreads();
  #pragma unroll
  for (int rr = 0; rr < 8; ++rr) {
    double v = bufA[rr][t] / mnorm[rr];
    hn64[(size_t)(row0 + rr) * DD + t] = v;
    unsigned short bv = f2bf((float)v);
    hnb[(size_t)(row0 + rr) * DD + t] = bv;
    rowb[rr][t] = bv;
  }
  __syncthreads();
  // pre-swizzled unit write: 128 units (8 rows x 16 units of 16B)
  {
    const int rr = t >> 4, c = (t >> 2) & 3, g = t & 3;
    const int rloc = (row0 & 127) + rr;
    const int q = (g - (rloc >> 1)) & 3;
    const int k0 = c * 32 + q * 8;
    uint4 u4 = *(const uint4*)&rowb[rr][k0];
    hnbs[(size_t)(row0 >> 7) * 2048 + c * 512 + rloc * 4 + g] = u4;
  }
}

// ---------------- Kernel 2: per-row float threshold from 512-col sample (R9-verified) ----------------
__global__ __launch_bounds__(256)
void tau_kernel(const unsigned short* __restrict__ hnb,
                float* __restrict__ tauf) {
  __shared__ unsigned short rowbuf[TROWS * DD];                           // 4 KB
  __shared__ __attribute__((aligned(16))) unsigned short sbuf[512 * 8];  // 8 KB
  const int t = threadIdx.x, lane = t & 63, wv = t >> 6;
  const int row0 = blockIdx.x * TROWS;

  #pragma unroll
  for (int i = 0; i < 4; ++i)
    ((unsigned*)rowbuf)[t + 256 * i] =
        ((const unsigned*)(hnb + (size_t)row0 * DD))[t + 256 * i];

  float acc[4][8];
  #pragma unroll
  for (int rr = 0; rr < 4; ++rr)
    #pragma unroll
    for (int s = 0; s < 8; ++s) acc[rr][s] = 0.0f;

  for (int k8 = 0; k8 < 16; ++k8) {
    __syncthreads();
    ((uint4*)sbuf)[t]       = *(const uint4*)(hnb + (size_t)t * DD + k8 * 8);
    ((uint4*)sbuf)[t + 256] = *(const uint4*)(hnb + (size_t)(t + 256) * DD + k8 * 8);
    __syncthreads();

    float rv[4][8];
    #pragma unroll
    for (int rr = 0; rr < 4; ++rr)
      #pragma unroll
      for (int e2 = 0; e2 < 4; ++e2) {
        unsigned w = ((const unsigned*)rowbuf)[(wv * 4 + rr) * 64 + k8 * 4 + e2];
        rv[rr][2 * e2]     = bf2f(w);
        rv[rr][2 * e2 + 1] = bf2f(w >> 16);
      }
    #pragma unroll
    for (int s = 0; s < 8; ++s) {
      uint4 cv = *(const uint4*)(sbuf + (lane + 64 * s) * 8);
      unsigned wd[4] = {cv.x, cv.y, cv.z, cv.w};
      #pragma unroll
      for (int rr = 0; rr < 4; ++rr)
        #pragma unroll
        for (int q = 0; q < 4; ++q) {
          acc[rr][s] = fmaf(bf2f(wd[q]),       rv[rr][2 * q],     acc[rr][s]);
          acc[rr][s] = fmaf(bf2f(wd[q] >> 16), rv[rr][2 * q + 1], acc[rr][s]);
        }
    }
  }

  #pragma unroll
  for (int rr = 0; rr < 4; ++rr) {
    unsigned key[8];
    #pragma unroll
    for (int s = 0; s < 8; ++s) {
      unsigned bf = f2bf(acc[rr][s]);
      key[s] = (bf & 0x8000u) ? 0u : bf;
    }
    unsigned lo = 0, hi = 0xFFFFu;
    while (lo < hi) {
      unsigned mid = (lo + hi + 1) >> 1;
      int c = 0;
      #pragma unroll
      for (int s = 0; s < 8; ++s) c += (int)(key[s] >= mid);
      #pragma unroll
      for (int d = 1; d < 64; d <<= 1) c += __shfl_xor(c, d);
      if (c >= TAURANK) lo = mid; else hi = mid - 1;
    }
    if (lane == 0) {
      unsigned tl = lo ? lo - 1 : 0;
      tauf[row0 + wv * 4 + rr] = tl ? 0.5f * (bf2f(tl - 1) + bf2f(tl)) : -2.0f;
    }
  }
}

// ---------------- Kernel 3: MFMA GEMM + float-threshold filter (pre-swizzled staging) ----------------
__device__ __forceinline__ int lunit(int c, int r, int q) {
  return c * 512 + r * 4 + ((q + (r >> 1)) & 3);
}

__global__ __launch_bounds__(256)
void gemm_filter_kernel(const uint4* __restrict__ hnbs,
                        const float* __restrict__ tauf,
                        int* __restrict__ cnt, unsigned* __restrict__ cand) {
  __shared__ __attribute__((aligned(16))) unsigned short At[16384];  // 32 KB
  __shared__ __attribute__((aligned(16))) unsigned short Bt[16384];  // 32 KB
  __shared__ int lcnt[TILE];
  const int t = threadIdx.x;
  const int lane = t & 63;
  const int wv = t >> 6;
  const int rowtile = blockIdx.x >> 2, chunk = blockIdx.x & 3;
  const int r0 = rowtile * TILE;

  // A stage: linear copy of pre-swizzled tile image
  {
    const uint4* asrc = hnbs + (size_t)rowtile * 2048;
    #pragma unroll
    for (int i = 0; i < 8; ++i)
      ((uint4*)At)[i * 256 + t] = asrc[i * 256 + t];
  }
  if (t < TILE) lcnt[t] = 0;

  const int wr = (wv >> 1) * 64;
  const int wc = (wv & 1) * 64;
  const int m = lane & 15, quad = lane >> 4;

  float tr[4][4];
  #pragma unroll
  for (int i = 0; i < 4; ++i)
    #pragma unroll
    for (int r = 0; r < 4; ++r)
      tr[i][r] = tauf[r0 + wr + i * 16 + quad * 4 + r];

  for (int tile = 0; tile < NT; ++tile) {
    __syncthreads();
    const int ctile = chunk * NT + tile;
    const int c0t = ctile * TILE;
    {
      const uint4* bsrc = hnbs + (size_t)ctile * 2048;
      #pragma unroll
      for (int i = 0; i < 8; ++i)
        ((uint4*)Bt)[i * 256 + t] = bsrc[i * 256 + t];
    }
    __syncthreads();

    f32x4 acc[4][4] = {};
    #pragma unroll
    for (int kc = 0; kc < 4; ++kc) {
      bf16x8 a[4], b[4];
      #pragma unroll
      for (int i = 0; i < 4; ++i)
        a[i] = *(const bf16x8*)(At + lunit(kc, wr + i * 16 + m, quad) * 8);
      #pragma unroll
      for (int j = 0; j < 4; ++j)
        b[j] = *(const bf16x8*)(Bt + lunit(kc, wc + j * 16 + m, quad) * 8);
      #pragma unroll
      for (int i = 0; i < 4; ++i)
        #pragma unroll
        for (int j = 0; j < 4; ++j)
          acc[i][j] = __builtin_amdgcn_mfma_f32_16x16x32_bf16(a[i], b[j], acc[i][j], 0, 0, 0);
    }

    // epilogue: max-gated float compare, LDS slot reservation, plain store
    #pragma unroll
    for (int i = 0; i < 4; ++i)
      #pragma unroll
      for (int r = 0; r < 4; ++r) {
        const int Rl = wr + i * 16 + quad * 4 + r;
        const float tv = tr[i][r];
        float m01 = fmaxf(acc[i][0][r], acc[i][1][r]);
        float m23 = fmaxf(acc[i][2][r], acc[i][3][r]);
        if (fmaxf(m01, m23) >= tv) {
          #pragma unroll
          for (int j = 0; j < 4; ++j) {
            float v = acc[i][j][r];
            if (v >= tv) {
              unsigned bf = f2bf(v);
              unsigned key = (bf & 0x8000u) ? 0u : bf;
              int slot = atomicAdd(&lcnt[Rl], 1);
              int C = c0t + wc + j * 16 + m;
              if (slot < CAPC)
                cand[((size_t)(r0 + Rl) * NCH + chunk) * CAPC + slot] =
                    (key << 16) | (unsigned)C;
            }
          }
        }
      }
  }

  __syncthreads();
  if (t < TILE) cnt[(r0 + t) * NCH + chunk] = lcnt[t];
}

// ---------------- Kernel 4: select (R9-verbatim) + cooperative fp64 rescore + fused emit ----------------
__global__ __launch_bounds__(256)
void rescore_emit_kernel(const unsigned* __restrict__ cand, const int* __restrict__ cnt,
                         const double* __restrict__ hn64, float* __restrict__ out) {
  __shared__ unsigned scand[4][CCAP];
  __shared__ float sval[4][KTOP];
  __shared__ int scol[4][KTOP];
  const int t = threadIdx.x, lane = t & 63, wv = t >> 6;
  const int row0blk = blockIdx.x * 4;
  const int row = row0blk + wv;

  // zero-fill this block's 4 output rows (overlaps compute; drained by the
  // pre-scatter __syncthreads, which emits s_waitcnt vmcnt(0) before s_barrier)
  {
    float4* ob = (float4*)(out + (size_t)row0blk * NN);
    const float4 z = {0.0f, 0.0f, 0.0f, 0.0f};
    #pragma unroll
    for (int i = 0; i < 4 * NN / 4 / 256; ++i)
      ob[i * 256 + t] = z;
  }

  int nseg[NCH];
  #pragma unroll
  for (int s = 0; s < NCH; ++s) {
    int n = cnt[row * NCH + s];
    nseg[s] = n > CAPC ? CAPC : n;
  }
  const unsigned* crow = cand + (size_t)row * CAPT;

  unsigned ck[CAPT / 64];
  bool vl[CAPT / 64];
  #pragma unroll
  for (int i = 0; i < CAPT / 64; ++i) {
    int idx = lane + 64 * i;
    int seg = idx / CAPC, slot = idx - seg * CAPC;
    bool v = slot < nseg[seg];
    vl[i] = v;
    ck[i] = v ? crow[idx] : 0u;
  }

  unsigned lo = 0, hi = 0xFFFFu;
  while (lo < hi) {
    unsigned mid = (lo + hi + 1) >> 1;
    int c = 0;
    #pragma unroll
    for (int i = 0; i < CAPT / 64; ++i) c += (int)((ck[i] >> 16) >= mid);
    #pragma unroll
    for (int d = 1; d < 64; d <<= 1) c += __shfl_xor(c, d);
    if (c >= TCAND) lo = mid; else hi = mid - 1;
  }
  const unsigned thr = lo;

  int cl = 0;
  #pragma unroll
  for (int i = 0; i < CAPT / 64; ++i)
    cl += (int)(vl[i] && ((ck[i] >> 16) >= thr));
  int pre = cl;
  #pragma unroll
  for (int d = 1; d < 64; d <<= 1) {
    int y = __shfl_up(pre, d);
    if (lane >= d) pre += y;
  }
  const int total = __shfl(pre, 63);
  const int nc = total < CCAP ? total : CCAP;
  int slot = pre - cl;
  #pragma unroll
  for (int i = 0; i < CAPT / 64; ++i) {
    if (vl[i] && ((ck[i] >> 16) >= thr)) {
      if (slot < CCAP) scand[wv][slot] = ck[i];
      ++slot;
    }
  }
  __syncthreads();

  // cooperative fp64 rescore (R9-verified): 64 lanes dot one candidate row,
  // 4 in flight; fp64 noise << rank gaps -> selection invariant.
  const double2 a2 = *(const double2*)(hn64 + (size_t)row * DD + 2 * lane);
  double rv0 = -1.0e300, rv1 = -1.0e300;
  int rc0 = 0x7fffffff, rc1 = 0x7fffffff;
  for (int c = 0; c < nc; c += 4) {
    double p[4]; int cols[4];
    #pragma unroll
    for (int u = 0; u < 4; ++u) {
      int cc = c + u;
      int ccl = cc < nc ? cc : nc - 1;
      int col = (int)(scand[wv][ccl] & 0xFFFFu);
      cols[u] = col;
      double2 b2 = *(const double2*)(hn64 + (size_t)col * DD + 2 * lane);
      p[u] = fma(a2.x, b2.x, a2.y * b2.y);
    }
    #pragma unroll
    for (int d = 1; d < 64; d <<= 1)
      #pragma unroll
      for (int u = 0; u < 4; ++u) p[u] += __shfl_xor(p[u], d);
    #pragma unroll
    for (int u = 0; u < 4; ++u) {
      int cc = c + u;
      if (cc < nc && (cc & 63) == lane) {
        if (cc < 64) { rv0 = p[u]; rc0 = cols[u]; }
        else         { rv1 = p[u]; rc1 = cols[u]; }
      }
    }
  }

  for (int itk = 0; itk < KTOP; ++itk) {
    bool f = (rv0 > rv1) || (rv0 == rv1 && rc0 < rc1);
    double bv = f ? rv0 : rv1;
    int bc = f ? rc0 : rc1;
    #pragma unroll
    for (int d = 1; d < 64; d <<= 1) {
      double ov = __shfl_xor(bv, d);
      int    oc = __shfl_xor(bc, d);
      bool tk = (ov > bv) || (ov == bv && oc < bc);
      bv = tk ? ov : bv;
      bc = tk ? oc : bc;
    }
    if (lane == itk) {
      sval[wv][itk] = (float)fmax(bv, 0.0);
      scol[wv][itk] = bc;
    }
    if (rv0 == bv && rc0 == bc) rv0 = -1.0e300;
    else if (rv1 == bv && rc1 == bc) rv1 = -1.0e300;
  }

  __syncthreads();   // drains zero-stores (vmcnt 0) + sval/scol visible
  if (lane < KTOP)
    out[(size_t)row * NN + scol[wv][lane]] = sval[wv][lane];
}

extern "C" void kernel_launch(void* const* d_in, const int* in_sizes, int n_in,
                              void* d_out, int out_size, void* d_ws, size_t ws_size,
                              hipStream_t stream) {
  const float* feat = (const float*)d_in[0];
  const float* W1 = (const float*)d_in[1];
  const float* b1 = (const float*)d_in[2];
  const float* W2 = (const float*)d_in[3];
  const float* b2 = (const float*)d_in[4];
  float* out = (float*)d_out;

  // ws: hn64 12.6MB | hnbs 3.1MB | hnb 3.1MB | cand 75.5MB | cnt 196KB | tauf 48KB  (~94.6MB)
  double* hn64 = (double*)d_ws;
  uint4* hnbs = (uint4*)(hn64 + (size_t)NN * DD);
  unsigned short* hnb = (unsigned short*)(hnbs + (size_t)RB * 2048);
  unsigned* cand = (unsigned*)(hnb + (size_t)NN * DD);
  int* cnt = (int*)(cand + (size_t)NN * CAPT);
  float* tauf = (float*)(cnt + NN * NCH);

  mlp_norm_kernel<<<NN / 8, 128, 0, stream>>>(feat, W1, b1, W2, b2, hn64, hnb, hnbs);
  tau_kernel<<<NN / TROWS, 256, 0, stream>>>(hnb, tauf);
  gemm_filter_kernel<<<RB * NCH, 256, 0, stream>>>(hnbs, tauf, cnt, cand);
  rescore_emit_kernel<<<NN / 4, 256, 0, stream>>>(cand, cnt, hn64, out);
}